// Round 11
// baseline (191.733 us; speedup 1.0000x reference)
//
#include <hip/hip_runtime.h>
#include <hip/hip_bf16.h>
#include <math.h>

typedef short short8 __attribute__((ext_vector_type(8)));
typedef float floatx4 __attribute__((ext_vector_type(4)));

__device__ __forceinline__ ushort f2bf(float f) {
    __hip_bfloat16 h = __float2bfloat16(f);
    return *reinterpret_cast<ushort*>(&h);
}
__device__ __forceinline__ void bf8_to_f32(uint4 u, float* f) {
    f[0] = __uint_as_float(u.x << 16); f[1] = __uint_as_float(u.x & 0xffff0000u);
    f[2] = __uint_as_float(u.y << 16); f[3] = __uint_as_float(u.y & 0xffff0000u);
    f[4] = __uint_as_float(u.z << 16); f[5] = __uint_as_float(u.z & 0xffff0000u);
    f[6] = __uint_as_float(u.w << 16); f[7] = __uint_as_float(u.w & 0xffff0000u);
}

// ---------------------------------------------------------------------------
// Prep: grid (16,16,7), block (32,8). (unchanged)
__global__ __launch_bounds__(256) void prep_kernel(
        const float* __restrict__ W1, const float* __restrict__ W2,
        const float* __restrict__ Wq, const float* __restrict__ Wk,
        const float* __restrict__ Wv, const float* __restrict__ Wo,
        const float* __restrict__ bq, const float* __restrict__ bv,
        const float* __restrict__ query,
        ushort* __restrict__ W1t, ushort* __restrict__ W2t,
        ushort* __restrict__ Wqkvt, ushort* __restrict__ Wot,
        ushort* __restrict__ queryB, float* __restrict__ biasC) {
    const int z = blockIdx.z;
    const int tx = threadIdx.x, ty = threadIdx.y;
    const int tid = ty * 32 + tx;
    if (z < 6) {
        const float* src; ushort* dst; int R;
        switch (z) {
            case 0:  src = W1; dst = W1t;              R = 256; break;
            case 1:  src = W2; dst = W2t;              R = 512; break;
            case 2:  src = Wq; dst = Wqkvt;            R = 512; break;
            case 3:  src = Wk; dst = Wqkvt + 512*512;  R = 512; break;
            case 4:  src = Wv; dst = Wqkvt + 1024*512; R = 512; break;
            default: src = Wo; dst = Wot;              R = 512; break;
        }
        const int r0 = blockIdx.y * 32, c0 = blockIdx.x * 32;
        if (r0 >= R) return;
        __shared__ float t[32][33];
        for (int i = ty; i < 32; i += 8) t[i][tx] = src[(size_t)(r0 + i) * 512 + c0 + tx];
        __syncthreads();
        for (int i = ty; i < 32; i += 8) dst[(size_t)(c0 + i) * R + r0 + tx] = f2bf(t[tx][i]);
    } else {
        const int bid = blockIdx.y * 16 + blockIdx.x;
#pragma unroll
        for (int i = 0; i < 8; ++i) {
            size_t idx4 = (size_t)bid * 2048 + i * 256 + tid;
            float4 v = *(const float4*)(query + idx4 * 4);
            ushort4 o; o.x = f2bf(v.x); o.y = f2bf(v.y); o.z = f2bf(v.z); o.w = f2bf(v.w);
            *(ushort4*)(queryB + idx4 * 4) = o;
        }
        if (bid == 0) {
            for (int i = tid; i < 1536; i += 256)
                biasC[i] = (i < 512) ? bq[i] : ((i < 1024) ? 0.0f : bv[i - 1024]);
        }
    }
}

// ---------------------------------------------------------------------------
// Fused pe pipeline (unchanged).
__global__ __launch_bounds__(256) void pe_fused(
        const float* __restrict__ qpos,
        const ushort* __restrict__ W1t, const ushort* __restrict__ W2t,
        const float* __restrict__ b1, const float* __restrict__ b2,
        ushort* __restrict__ peB) {
    __shared__ ushort embS[16 * 256];   // 8 KB
    __shared__ ushort hidS[16 * 512];   // 16 KB
    const int tid = threadIdx.x;
    const int l = tid & 63, w = tid >> 6;
    const int l15 = l & 15, quad = l >> 4;
    const int r0 = blockIdx.x * 16;

    {
        const int e0 = tid * 16;
        const int row = e0 >> 8, j0 = e0 & 255;
        const float t = qpos[r0 + row];
        ushort o[16];
#pragma unroll
        for (int u = 0; u < 16; ++u) {
            int j = j0 + u, i = j & 127;
            float freq = __expf(-9.210340371976184f * (float)i * (1.0f / 128.0f));
            float a = t * freq;
            o[u] = f2bf((j < 128) ? __cosf(a) : __sinf(a));
        }
        *(uint4*)&embS[e0]     = *(uint4*)&o[0];
        *(uint4*)&embS[e0 + 8] = *(uint4*)&o[8];
    }
    __syncthreads();

    {
        floatx4 acc[8] = {};
        for (int k0 = 0; k0 < 256; k0 += 32) {
            short8 a = *(const short8*)&embS[l15 * 256 + k0 + quad * 8];
#pragma unroll
            for (int j = 0; j < 8; ++j) {
                short8 bf = *(const short8*)(W1t + (size_t)(w * 128 + j * 16 + l15) * 256 + k0 + quad * 8);
                acc[j] = __builtin_amdgcn_mfma_f32_16x16x32_bf16(a, bf, acc[j], 0, 0, 0);
            }
        }
#pragma unroll
        for (int j = 0; j < 8; ++j) {
            int col = w * 128 + j * 16 + l15;
            float bb = b1[col];
#pragma unroll
            for (int r = 0; r < 4; ++r) {
                int row = quad * 4 + r;
                float v = acc[j][r] + bb;
                v = v / (1.0f + __expf(-v));
                hidS[row * 512 + col] = f2bf(v);
            }
        }
    }
    __syncthreads();

    {
        floatx4 acc[8] = {};
        for (int k0 = 0; k0 < 512; k0 += 32) {
            short8 a = *(const short8*)&hidS[l15 * 512 + k0 + quad * 8];
#pragma unroll
            for (int j = 0; j < 8; ++j) {
                short8 bf = *(const short8*)(W2t + (size_t)(w * 128 + j * 16 + l15) * 512 + k0 + quad * 8);
                acc[j] = __builtin_amdgcn_mfma_f32_16x16x32_bf16(a, bf, acc[j], 0, 0, 0);
            }
        }
#pragma unroll
        for (int j = 0; j < 8; ++j) {
            int col = w * 128 + j * 16 + l15;
            float bb = b2[col];
#pragma unroll
            for (int r = 0; r < 4; ++r)
                peB[(size_t)(r0 + quad * 4 + r) * 512 + col] = f2bf(acc[j][r] + bb);
        }
    }
}

// ---------------------------------------------------------------------------
// Fused QKV projection + attention, v2.
// Grid (b=64 fastest, h=8): consecutive blocks share the pe h-slice in L2.
// LDS rows padded to 68 floats (conflict-free, float4-aligned).
// k/v register-cached per wave after one LDS pass (was the 63us bottleneck:
// 16x re-read of ks/vs per wave -> now 1x).
__global__ __launch_bounds__(256, 2) void qkv_attn(
        const ushort* __restrict__ queryB, const ushort* __restrict__ Wqkvt,
        const float* __restrict__ biasC, const ushort* __restrict__ peB,
        ushort* __restrict__ xB) {
    const int b = blockIdx.x, h = blockIdx.y;
    const int tid = threadIdx.x;
    const int l = tid & 63, w = tid >> 6;
    const int l15 = l & 15, quad = l >> 4;
    const int lo = l & 7, hi = l >> 3;

    __shared__ float qs[64 * 68];
    __shared__ float ks[64 * 68];
    __shared__ float vs[64 * 68];

    // --- GEMM phase: q/k/v = queryB[b rows] @ Wqkv slices, K=512
    {
        floatx4 acc[4][3] = {};
        const ushort* pa  = queryB + (size_t)(b * 64 + l15) * 512 + quad * 8;
        const int colL = w * 16 + l15;
        const ushort* pbq = Wqkvt + (size_t)(h * 64 + colL) * 512 + quad * 8;
        const ushort* pbk = pbq + (size_t)512 * 512;
        const ushort* pbv = pbq + (size_t)1024 * 512;
        for (int k0 = 0; k0 < 512; k0 += 32) {
            short8 a0 = *(const short8*)(pa + k0);
            short8 a1 = *(const short8*)(pa + (size_t)16 * 512 + k0);
            short8 a2 = *(const short8*)(pa + (size_t)32 * 512 + k0);
            short8 a3 = *(const short8*)(pa + (size_t)48 * 512 + k0);
            short8 bq_ = *(const short8*)(pbq + k0);
            short8 bk_ = *(const short8*)(pbk + k0);
            short8 bv_ = *(const short8*)(pbv + k0);
            acc[0][0] = __builtin_amdgcn_mfma_f32_16x16x32_bf16(a0, bq_, acc[0][0], 0, 0, 0);
            acc[1][0] = __builtin_amdgcn_mfma_f32_16x16x32_bf16(a1, bq_, acc[1][0], 0, 0, 0);
            acc[2][0] = __builtin_amdgcn_mfma_f32_16x16x32_bf16(a2, bq_, acc[2][0], 0, 0, 0);
            acc[3][0] = __builtin_amdgcn_mfma_f32_16x16x32_bf16(a3, bq_, acc[3][0], 0, 0, 0);
            acc[0][1] = __builtin_amdgcn_mfma_f32_16x16x32_bf16(a0, bk_, acc[0][1], 0, 0, 0);
            acc[1][1] = __builtin_amdgcn_mfma_f32_16x16x32_bf16(a1, bk_, acc[1][1], 0, 0, 0);
            acc[2][1] = __builtin_amdgcn_mfma_f32_16x16x32_bf16(a2, bk_, acc[2][1], 0, 0, 0);
            acc[3][1] = __builtin_amdgcn_mfma_f32_16x16x32_bf16(a3, bk_, acc[3][1], 0, 0, 0);
            acc[0][2] = __builtin_amdgcn_mfma_f32_16x16x32_bf16(a0, bv_, acc[0][2], 0, 0, 0);
            acc[1][2] = __builtin_amdgcn_mfma_f32_16x16x32_bf16(a1, bv_, acc[1][2], 0, 0, 0);
            acc[2][2] = __builtin_amdgcn_mfma_f32_16x16x32_bf16(a2, bv_, acc[2][2], 0, 0, 0);
            acc[3][2] = __builtin_amdgcn_mfma_f32_16x16x32_bf16(a3, bv_, acc[3][2], 0, 0, 0);
        }
        float bqb = biasC[h * 64 + colL];
        float bvb = biasC[1024 + h * 64 + colL];
#pragma unroll
        for (int i = 0; i < 4; ++i)
#pragma unroll
            for (int r = 0; r < 4; ++r) {
                int row = i * 16 + quad * 4 + r;
                qs[row * 68 + colL] = acc[i][0][r] + bqb;
                ks[row * 68 + colL] = acc[i][1][r];
                vs[row * 68 + colL] = acc[i][2][r] + bvb;
            }
    }
    __syncthreads();

    // --- register-cache k,v: lane (hi,lo) holds m = mg*8+hi, d = lo*8..+7
    float kr[8][8], vr[8][8];
#pragma unroll
    for (int mg = 0; mg < 8; ++mg) {
        int m = mg * 8 + hi;
        *(float4*)&kr[mg][0] = *(const float4*)&ks[m * 68 + lo * 8];
        *(float4*)&kr[mg][4] = *(const float4*)&ks[m * 68 + lo * 8 + 4];
        *(float4*)&vr[mg][0] = *(const float4*)&vs[m * 68 + lo * 8];
        *(float4*)&vr[mg][4] = *(const float4*)&vs[m * 68 + lo * 8 + 4];
    }

    // --- attention phase: wave-private n = w + 4*i
    for (int i = 0; i < 16; ++i) {
        const int n = w + 4 * i;
        float qf[8];
        *(float4*)&qf[0] = *(const float4*)&qs[n * 68 + lo * 8];
        *(float4*)&qf[4] = *(const float4*)&qs[n * 68 + lo * 8 + 4];

        float sreg[8];
#pragma unroll
        for (int mg = 0; mg < 8; ++mg) {
            int m = mg * 8 + hi;
            uint4 pu = *(const uint4*)(peB + (size_t)(n * 64 + m) * 512 + h * 64 + lo * 8);
            float pf[8]; bf8_to_f32(pu, pf);
            float p = 0.0f;
#pragma unroll
            for (int j = 0; j < 8; ++j) p = fmaf(qf[j] * kr[mg][j], pf[j], p);
            p += __shfl_xor(p, 1);
            p += __shfl_xor(p, 2);
            p += __shfl_xor(p, 4);
            sreg[mg] = p * 0.125f;   // HD^-0.5
        }

        float mx = sreg[0];
#pragma unroll
        for (int mg = 1; mg < 8; ++mg) mx = fmaxf(mx, sreg[mg]);
        mx = fmaxf(mx, __shfl_xor(mx, 8));
        mx = fmaxf(mx, __shfl_xor(mx, 16));
        mx = fmaxf(mx, __shfl_xor(mx, 32));
        float sum = 0.0f;
#pragma unroll
        for (int mg = 0; mg < 8; ++mg) { sreg[mg] = __expf(sreg[mg] - mx); sum += sreg[mg]; }
        sum += __shfl_xor(sum, 8);
        sum += __shfl_xor(sum, 16);
        sum += __shfl_xor(sum, 32);
        float rs = 1.0f / sum;

        float acc[8] = {};
#pragma unroll
        for (int mg = 0; mg < 8; ++mg) {
            float at = sreg[mg] * rs;
#pragma unroll
            for (int j = 0; j < 8; ++j) acc[j] = fmaf(at, vr[mg][j], acc[j]);
        }
#pragma unroll
        for (int j = 0; j < 8; ++j) {
            acc[j] += __shfl_xor(acc[j], 8);
            acc[j] += __shfl_xor(acc[j], 16);
            acc[j] += __shfl_xor(acc[j], 32);
        }
        if (l < 8) {
            uint4 o;
            o.x = f2bf(acc[0]) | ((uint)f2bf(acc[1]) << 16);
            o.y = f2bf(acc[2]) | ((uint)f2bf(acc[3]) << 16);
            o.z = f2bf(acc[4]) | ((uint)f2bf(acc[5]) << 16);
            o.w = f2bf(acc[6]) | ((uint)f2bf(acc[7]) << 16);
            *(uint4*)(xB + (size_t)(b * 64 + n) * 512 + h * 64 + l * 8) = o;
        }
    }
}

// ---------------------------------------------------------------------------
// Final GEMM: out = x @ Wo + bo + query (fp32 out). (unchanged)
__global__ __launch_bounds__(256, 2) void out_gemm(
        const ushort* __restrict__ xB, const ushort* __restrict__ Wot,
        const float* __restrict__ bo, const float* __restrict__ query,
        float* __restrict__ out) {
    const int tid = threadIdx.x;
    const int l = tid & 63, w = tid >> 6;
    const int l15 = l & 15, quad = l >> 4;
    const int row0 = blockIdx.x * 64 + w * 16;
    const int col0 = blockIdx.y * 64;

    floatx4 acc[4] = {};
    const ushort* pa = xB  + (size_t)(row0 + l15) * 512 + quad * 8;
    const ushort* pb = Wot + (size_t)(col0 + l15) * 512 + quad * 8;
    for (int k0 = 0; k0 < 512; k0 += 32) {
        short8 a = *(const short8*)(pa + k0);
#pragma unroll
        for (int j = 0; j < 4; ++j) {
            short8 bf = *(const short8*)(pb + (size_t)(j * 16) * 512 + k0);
            acc[j] = __builtin_amdgcn_mfma_f32_16x16x32_bf16(a, bf, acc[j], 0, 0, 0);
        }
    }
#pragma unroll
    for (int j = 0; j < 4; ++j) {
        int col = col0 + j * 16 + l15;
        float bb = bo[col];
#pragma unroll
        for (int r = 0; r < 4; ++r) {
            int row = row0 + quad * 4 + r;
            out[(size_t)row * 512 + col] = acc[j][r] + bb + query[(size_t)row * 512 + col];
        }
    }
}

// ---------------------------------------------------------------------------
extern "C" void kernel_launch(void* const* d_in, const int* in_sizes, int n_in,
                              void* d_out, int out_size, void* d_ws, size_t ws_size,
                              hipStream_t stream) {
    const float* query = (const float*)d_in[0];
    const float* qpos  = (const float*)d_in[1];
    const float* Wq    = (const float*)d_in[2];
    const float* bq    = (const float*)d_in[3];
    const float* Wk    = (const float*)d_in[4];
    const float* Wv    = (const float*)d_in[5];
    const float* bv    = (const float*)d_in[6];
    const float* Wo    = (const float*)d_in[7];
    const float* bo    = (const float*)d_in[8];
    const float* W1    = (const float*)d_in[9];
    const float* b1    = (const float*)d_in[10];
    const float* W2    = (const float*)d_in[11];
    const float* b2    = (const float*)d_in[12];
    float* out = (float*)d_out;
    char* ws = (char*)d_ws;

    ushort* W1t    = (ushort*)(ws + 0);          // [512][256]  256 KB
    ushort* W2t    = (ushort*)(ws + 262144);     // [512][512]  512 KB
    ushort* Wqkvt  = (ushort*)(ws + 786432);     // [1536][512] 1.5 MB
    ushort* Wot    = (ushort*)(ws + 2359296);    // [512][512]  512 KB
    float*  biasC  = (float*) (ws + 2883584);    // [1536]
    ushort* queryB = (ushort*)(ws + 5242880);    // [4096][512] 4 MB
    ushort* peB    = (ushort*)(ws + 13631488);   // [4096][512] 4 MB
    ushort* xB     = (ushort*)(ws + 30408704);   // [4096][512] 4 MB

    prep_kernel<<<dim3(16, 16, 7), dim3(32, 8), 0, stream>>>(
        W1, W2, Wq, Wk, Wv, Wo, bq, bv, query,
        W1t, W2t, Wqkvt, Wot, queryB, biasC);

    pe_fused<<<256, 256, 0, stream>>>(qpos, W1t, W2t, b1, b2, peB);

    qkv_attn<<<dim3(64, 8), 256, 0, stream>>>(queryB, Wqkvt, biasC, peB, xB);

    out_gemm<<<dim3(64, 8), 256, 0, stream>>>(xB, Wot, bo, query, out);
}

// Round 13
// 176.037 us; speedup vs baseline: 1.0892x; 1.0892x over previous
//
#include <hip/hip_runtime.h>
#include <hip/hip_bf16.h>
#include <math.h>

typedef short short8 __attribute__((ext_vector_type(8)));
typedef float floatx4 __attribute__((ext_vector_type(4)));

__device__ __forceinline__ ushort f2bf(float f) {
    __hip_bfloat16 h = __float2bfloat16(f);
    return *reinterpret_cast<ushort*>(&h);
}
__device__ __forceinline__ void bf8_to_f32(uint4 u, float* f) {
    f[0] = __uint_as_float(u.x << 16); f[1] = __uint_as_float(u.x & 0xffff0000u);
    f[2] = __uint_as_float(u.y << 16); f[3] = __uint_as_float(u.y & 0xffff0000u);
    f[4] = __uint_as_float(u.z << 16); f[5] = __uint_as_float(u.z & 0xffff0000u);
    f[6] = __uint_as_float(u.w << 16); f[7] = __uint_as_float(u.w & 0xffff0000u);
}

#define GLDS16(g, l) __builtin_amdgcn_global_load_lds( \
    (const __attribute__((address_space(1))) void*)(g), \
    (__attribute__((address_space(3))) void*)(l), 16, 0, 0)

// ---------------------------------------------------------------------------
// Prep: grid (16,16,7), block (32,8). (proven, unchanged)
__global__ __launch_bounds__(256) void prep_kernel(
        const float* __restrict__ W1, const float* __restrict__ W2,
        const float* __restrict__ Wq, const float* __restrict__ Wk,
        const float* __restrict__ Wv, const float* __restrict__ Wo,
        const float* __restrict__ bq, const float* __restrict__ bv,
        const float* __restrict__ query,
        ushort* __restrict__ W1t, ushort* __restrict__ W2t,
        ushort* __restrict__ Wqkvt, ushort* __restrict__ Wot,
        ushort* __restrict__ queryB, float* __restrict__ biasC) {
    const int z = blockIdx.z;
    const int tx = threadIdx.x, ty = threadIdx.y;
    const int tid = ty * 32 + tx;
    if (z < 6) {
        const float* src; ushort* dst; int R;
        switch (z) {
            case 0:  src = W1; dst = W1t;              R = 256; break;
            case 1:  src = W2; dst = W2t;              R = 512; break;
            case 2:  src = Wq; dst = Wqkvt;            R = 512; break;
            case 3:  src = Wk; dst = Wqkvt + 512*512;  R = 512; break;
            case 4:  src = Wv; dst = Wqkvt + 1024*512; R = 512; break;
            default: src = Wo; dst = Wot;              R = 512; break;
        }
        const int r0 = blockIdx.y * 32, c0 = blockIdx.x * 32;
        if (r0 >= R) return;
        __shared__ float t[32][33];
        for (int i = ty; i < 32; i += 8) t[i][tx] = src[(size_t)(r0 + i) * 512 + c0 + tx];
        __syncthreads();
        for (int i = ty; i < 32; i += 8) dst[(size_t)(c0 + i) * R + r0 + tx] = f2bf(t[tx][i]);
    } else {
        const int bid = blockIdx.y * 16 + blockIdx.x;
#pragma unroll
        for (int i = 0; i < 8; ++i) {
            size_t idx4 = (size_t)bid * 2048 + i * 256 + tid;
            float4 v = *(const float4*)(query + idx4 * 4);
            ushort4 o; o.x = f2bf(v.x); o.y = f2bf(v.y); o.z = f2bf(v.z); o.w = f2bf(v.w);
            *(ushort4*)(queryB + idx4 * 4) = o;
        }
        if (bid == 0) {
            for (int i = tid; i < 1536; i += 256)
                biasC[i] = (i < 512) ? bq[i] : ((i < 1024) ? 0.0f : bv[i - 1024]);
        }
    }
}

// ---------------------------------------------------------------------------
// Fused pe pipeline, 512 threads = 8 waves. Wave w owns cols w*64..w*64+63.
__global__ __launch_bounds__(512) void pe_fused(
        const float* __restrict__ qpos,
        const ushort* __restrict__ W1t, const ushort* __restrict__ W2t,
        const float* __restrict__ b1, const float* __restrict__ b2,
        ushort* __restrict__ peB) {
    __shared__ ushort embS[16 * 256];   // 8 KB
    __shared__ ushort hidS[16 * 512];   // 16 KB
    const int tid = threadIdx.x;
    const int l = tid & 63, w = tid >> 6;
    const int l15 = l & 15, quad = l >> 4;
    const int r0 = blockIdx.x * 16;

    {
        const int e0 = tid * 8;
        const int row = e0 >> 8, j0 = e0 & 255;
        const float t = qpos[r0 + row];
        ushort o[8];
#pragma unroll
        for (int u = 0; u < 8; ++u) {
            int j = j0 + u, i = j & 127;
            float freq = __expf(-9.210340371976184f * (float)i * (1.0f / 128.0f));
            float a = t * freq;
            o[u] = f2bf((j < 128) ? __cosf(a) : __sinf(a));
        }
        *(uint4*)&embS[e0] = *(uint4*)&o[0];
    }
    __syncthreads();

    {
        floatx4 acc[4] = {};
        for (int k0 = 0; k0 < 256; k0 += 32) {
            short8 a = *(const short8*)&embS[l15 * 256 + k0 + quad * 8];
#pragma unroll
            for (int j = 0; j < 4; ++j) {
                short8 bf = *(const short8*)(W1t + (size_t)(w * 64 + j * 16 + l15) * 256 + k0 + quad * 8);
                acc[j] = __builtin_amdgcn_mfma_f32_16x16x32_bf16(a, bf, acc[j], 0, 0, 0);
            }
        }
#pragma unroll
        for (int j = 0; j < 4; ++j) {
            int col = w * 64 + j * 16 + l15;
            float bb = b1[col];
#pragma unroll
            for (int r = 0; r < 4; ++r) {
                int row = quad * 4 + r;
                float v = acc[j][r] + bb;
                v = v / (1.0f + __expf(-v));
                hidS[row * 512 + col] = f2bf(v);
            }
        }
    }
    __syncthreads();

    {
        floatx4 acc[4] = {};
        for (int k0 = 0; k0 < 512; k0 += 32) {
            short8 a = *(const short8*)&hidS[l15 * 512 + k0 + quad * 8];
#pragma unroll
            for (int j = 0; j < 4; ++j) {
                short8 bf = *(const short8*)(W2t + (size_t)(w * 64 + j * 16 + l15) * 512 + k0 + quad * 8);
                acc[j] = __builtin_amdgcn_mfma_f32_16x16x32_bf16(a, bf, acc[j], 0, 0, 0);
            }
        }
#pragma unroll
        for (int j = 0; j < 4; ++j) {
            int col = w * 64 + j * 16 + l15;
            float bb = b2[col];
#pragma unroll
            for (int r = 0; r < 4; ++r)
                peB[(size_t)(r0 + quad * 4 + r) * 512 + col] = f2bf(acc[j][r] + bb);
        }
    }
}

// ---------------------------------------------------------------------------
// bf16 MFMA GEMM, GLDS16 staging (round-5-proven). 64x64 tile, BK=32.
__global__ __launch_bounds__(256) void gemm_bf16(
        const ushort* __restrict__ A, const ushort* __restrict__ Bt,
        const float* __restrict__ bias, const float* __restrict__ resid,
        void* __restrict__ Cout, int M, int N, int K, int act, int out_fp32) {
    __shared__ ushort As[64 * 32];
    __shared__ ushort Bs[64 * 32];
    const int tid = threadIdx.x;
    const int l = tid & 63, w = tid >> 6;
    const int wr = w >> 1, wc = w & 1;
    const int row0 = blockIdx.x * 64, col0 = blockIdx.y * 64;
    const int l15 = l & 15, quad = l >> 4;
    const int arow = w * 16 + (l >> 2), koff = (l & 3) * 8;

    const ushort* gA = A  + (size_t)(row0 + arow) * K + koff;
    const ushort* gB = Bt + (size_t)(col0 + arow) * K + koff;
    ushort* lA = &As[w * 512 + l * 8];
    ushort* lB = &Bs[w * 512 + l * 8];

    floatx4 acc[2][2] = {};

    for (int k0 = 0; k0 < K; k0 += 32) {
        __syncthreads();
        GLDS16(gA + k0, lA);
        GLDS16(gB + k0, lB);
        __syncthreads();
        short8 a0 = *(const short8*)&As[(wr * 32 + l15) * 32 + quad * 8];
        short8 a1 = *(const short8*)&As[(wr * 32 + 16 + l15) * 32 + quad * 8];
        short8 b0 = *(const short8*)&Bs[(wc * 32 + l15) * 32 + quad * 8];
        short8 b1 = *(const short8*)&Bs[(wc * 32 + 16 + l15) * 32 + quad * 8];
        acc[0][0] = __builtin_amdgcn_mfma_f32_16x16x32_bf16(a0, b0, acc[0][0], 0, 0, 0);
        acc[0][1] = __builtin_amdgcn_mfma_f32_16x16x32_bf16(a0, b1, acc[0][1], 0, 0, 0);
        acc[1][0] = __builtin_amdgcn_mfma_f32_16x16x32_bf16(a1, b0, acc[1][0], 0, 0, 0);
        acc[1][1] = __builtin_amdgcn_mfma_f32_16x16x32_bf16(a1, b1, acc[1][1], 0, 0, 0);
    }

#pragma unroll
    for (int i = 0; i < 2; ++i)
#pragma unroll
        for (int j = 0; j < 2; ++j) {
            int col = col0 + wc * 32 + j * 16 + l15;
            float bvv = bias ? bias[col] : 0.0f;
#pragma unroll
            for (int r = 0; r < 4; ++r) {
                int row = row0 + wr * 32 + i * 16 + quad * 4 + r;
                float val = acc[i][j][r] + bvv;
                if (act) val = val / (1.0f + __expf(-val));
                if (out_fp32) {
                    float rv = resid ? resid[(size_t)row * N + col] : 0.0f;
                    ((float*)Cout)[(size_t)row * N + col] = val + rv;
                } else {
                    ((ushort*)Cout)[(size_t)row * N + col] = f2bf(val);
                }
            }
        }
}

// ---------------------------------------------------------------------------
// Attention, high-occupancy: grid (b=64, h=8, ng=4) = 2048 blocks, 256 thr
// -> 8 blocks/CU = 32 waves/CU (LDS 16 KB). Each block: 16 n for one (b,h).
// k/v staged bf16 in LDS (FIXED staging: 1024 x 16B chunks = 4/thread,
// row = c>>3, ch = c&7 -> gap-free 64-ushort rows).
__global__ __launch_bounds__(256) void attn_hi(
        const ushort* __restrict__ qkv, const ushort* __restrict__ peB,
        ushort* __restrict__ xB) {
    const int b = blockIdx.x, h = blockIdx.y, ng = blockIdx.z;
    const int tid = threadIdx.x;
    const int w = tid >> 6, l = tid & 63;
    const int lo = l & 7, hi = l >> 3;

    __shared__ ushort ksB[64 * 64];   // 8 KB
    __shared__ ushort vsB[64 * 64];   // 8 KB

    // stage k,v: 2 matrices x 64 rows x 8 chunks x 8 ushorts = 1024 chunks
#pragma unroll
    for (int p = 0; p < 4; ++p) {
        int idx = p * 256 + tid;          // 0..1023
        int mat = idx >> 9, c = idx & 511;
        int row = c >> 3, ch = c & 7;
        const ushort* src = qkv + (size_t)(b * 64 + row) * 1536
                          + (mat ? 1024 : 512) + h * 64 + ch * 8;
        uint4 u = *(const uint4*)src;
        ushort* dst = (mat ? vsB : ksB) + row * 64 + ch * 8;
        *(uint4*)dst = u;
    }
    __syncthreads();

    // each wave: 4 n values
    for (int i = 0; i < 4; ++i) {
        const int n = ng * 16 + w + 4 * i;
        uint4 qu = *(const uint4*)(qkv + (size_t)(b * 64 + n) * 1536 + h * 64 + lo * 8);
        float qf[8]; bf8_to_f32(qu, qf);

        float sreg[8];
#pragma unroll
        for (int mg = 0; mg < 8; ++mg) {
            int m = mg * 8 + hi;
            uint4 pu = *(const uint4*)(peB + (size_t)(n * 64 + m) * 512 + h * 64 + lo * 8);
            float pf[8]; bf8_to_f32(pu, pf);
            uint4 ku = *(const uint4*)&ksB[m * 64 + lo * 8];
            float kf[8]; bf8_to_f32(ku, kf);
            float p = 0.0f;
#pragma unroll
            for (int j = 0; j < 8; ++j) p = fmaf(qf[j] * kf[j], pf[j], p);
            p += __shfl_xor(p, 1);
            p += __shfl_xor(p, 2);
            p += __shfl_xor(p, 4);
            sreg[mg] = p * 0.125f;   // HD^-0.5
        }

        float mx = sreg[0];
#pragma unroll
        for (int mg = 1; mg < 8; ++mg) mx = fmaxf(mx, sreg[mg]);
        mx = fmaxf(mx, __shfl_xor(mx, 8));
        mx = fmaxf(mx, __shfl_xor(mx, 16));
        mx = fmaxf(mx, __shfl_xor(mx, 32));
        float sum = 0.0f;
#pragma unroll
        for (int mg = 0; mg < 8; ++mg) { sreg[mg] = __expf(sreg[mg] - mx); sum += sreg[mg]; }
        sum += __shfl_xor(sum, 8);
        sum += __shfl_xor(sum, 16);
        sum += __shfl_xor(sum, 32);
        float rs = 1.0f / sum;

        float acc[8] = {};
#pragma unroll
        for (int mg = 0; mg < 8; ++mg) {
            int m = mg * 8 + hi;
            float at = sreg[mg] * rs;
            uint4 vu = *(const uint4*)&vsB[m * 64 + lo * 8];
            float vf[8]; bf8_to_f32(vu, vf);
#pragma unroll
            for (int j = 0; j < 8; ++j) acc[j] = fmaf(at, vf[j], acc[j]);
        }
#pragma unroll
        for (int j = 0; j < 8; ++j) {
            acc[j] += __shfl_xor(acc[j], 8);
            acc[j] += __shfl_xor(acc[j], 16);
            acc[j] += __shfl_xor(acc[j], 32);
        }
        if (l < 8) {
            uint4 o;
            o.x = f2bf(acc[0]) | ((uint)f2bf(acc[1]) << 16);
            o.y = f2bf(acc[2]) | ((uint)f2bf(acc[3]) << 16);
            o.z = f2bf(acc[4]) | ((uint)f2bf(acc[5]) << 16);
            o.w = f2bf(acc[6]) | ((uint)f2bf(acc[7]) << 16);
            *(uint4*)(xB + (size_t)(b * 64 + n) * 512 + h * 64 + l * 8) = o;
        }
    }
}

// ---------------------------------------------------------------------------
extern "C" void kernel_launch(void* const* d_in, const int* in_sizes, int n_in,
                              void* d_out, int out_size, void* d_ws, size_t ws_size,
                              hipStream_t stream) {
    const float* query = (const float*)d_in[0];
    const float* qpos  = (const float*)d_in[1];
    const float* Wq    = (const float*)d_in[2];
    const float* bq    = (const float*)d_in[3];
    const float* Wk    = (const float*)d_in[4];
    const float* Wv    = (const float*)d_in[5];
    const float* bv    = (const float*)d_in[6];
    const float* Wo    = (const float*)d_in[7];
    const float* bo    = (const float*)d_in[8];
    const float* W1    = (const float*)d_in[9];
    const float* b1    = (const float*)d_in[10];
    const float* W2    = (const float*)d_in[11];
    const float* b2    = (const float*)d_in[12];
    float* out = (float*)d_out;
    char* ws = (char*)d_ws;

    ushort* W1t    = (ushort*)(ws + 0);          // [512][256]  256 KB
    ushort* W2t    = (ushort*)(ws + 262144);     // [512][512]  512 KB
    ushort* Wqkvt  = (ushort*)(ws + 786432);     // [1536][512] 1.5 MB
    ushort* Wot    = (ushort*)(ws + 2359296);    // [512][512]  512 KB
    float*  biasC  = (float*) (ws + 2883584);    // [1536]
    ushort* queryB = (ushort*)(ws + 5242880);    // [4096][512] 4 MB
    ushort* peB    = (ushort*)(ws + 13631488);   // [4096][512] 4 MB
    ushort* qkvB   = (ushort*)(ws + 17825792);   // [4096][1536] 12 MB
    ushort* xB     = (ushort*)(ws + 30408704);   // [4096][512] 4 MB

    prep_kernel<<<dim3(16, 16, 7), dim3(32, 8), 0, stream>>>(
        W1, W2, Wq, Wk, Wv, Wo, bq, bv, query,
        W1t, W2t, Wqkvt, Wot, queryB, biasC);

    pe_fused<<<256, 512, 0, stream>>>(qpos, W1t, W2t, b1, b2, peB);

    gemm_bf16<<<dim3(64, 24), 256, 0, stream>>>(queryB, Wqkvt, biasC, nullptr,
                                                qkvB, 4096, 1536, 512, 0, 0);

    attn_hi<<<dim3(64, 8, 4), 256, 0, stream>>>(qkvB, peB, xB);

    gemm_bf16<<<dim3(64, 8), 256, 0, stream>>>(xB, Wot, bo, query, out,
                                               4096, 512, 512, 0, 1);
}